// Round 4
// baseline (5091.641 us; speedup 1.0000x reference)
//
#include <hip/hip_runtime.h>
#include <stdint.h>

typedef unsigned int uint;
typedef unsigned short ushort;

#define NB_MAX 1600   // buckets = ceil(N/64); N=100000 -> 1563

__device__ __forceinline__ ushort f2bf(float f) {
    uint u = __float_as_uint(f);
    return (ushort)((u + 0x7fffu + ((u >> 16) & 1u)) >> 16);   // RNE
}
__device__ __forceinline__ float bf2f(ushort h) {
    return __uint_as_float(((uint)h) << 16);
}

// ---- bucket histogram (64-row buckets), LDS-aggregated --------------------

__global__ __launch_bounds__(256) void k_bhist(const int* __restrict__ rows,
                                               uint* __restrict__ bhist, int nnz, int nb) {
    __shared__ uint h[NB_MAX];
    for (int j = threadIdx.x; j < nb; j += blockDim.x) h[j] = 0;
    __syncthreads();
    int stride = gridDim.x * blockDim.x;
    for (int i = blockIdx.x * blockDim.x + threadIdx.x; i < nnz; i += stride)
        atomicAdd(&h[rows[i] >> 6], 1u);
    __syncthreads();
    for (int j = threadIdx.x; j < nb; j += blockDim.x) {
        uint c = h[j];
        if (c) atomicAdd(&bhist[j], c);
    }
}

// ---- single-block exclusive scan over nb buckets --------------------------

__global__ __launch_bounds__(256) void k_scan(const uint* __restrict__ bhist,
                                              uint* __restrict__ off, uint* __restrict__ cur,
                                              int nb, int nnz) {
    __shared__ uint wsum[4];
    __shared__ uint carry;
    int t = threadIdx.x, lane = t & 63, wv = t >> 6;
    if (t == 0) carry = 0;
    __syncthreads();
    for (int base = 0; base < nb; base += 256) {
        int i = base + t;
        uint v = (i < nb) ? bhist[i] : 0u;
        uint inc = v;
#pragma unroll
        for (int o = 1; o < 64; o <<= 1) { uint u = __shfl_up(inc, o); if (lane >= o) inc += u; }
        if (lane == 63) wsum[wv] = inc;
        __syncthreads();
        uint woff = 0;
        for (int k = 0; k < wv; k++) woff += wsum[k];
        uint excl = carry + woff + (inc - v);
        if (i < nb) { off[i] = excl; cur[i] = excl; }
        uint tot = wsum[0] + wsum[1] + wsum[2] + wsum[3];
        __syncthreads();
        if (t == 0) carry += tot;
        __syncthreads();
    }
    if (t == 0) off[nb] = (uint)nnz;
}

// ---- two-pass binning: edges -> bucket-contiguous records -----------------
// record: (localrow6 << 17) | col17 , val. One global atomic per (bucket,block).

__global__ __launch_bounds__(512) void k_binpass(const int* __restrict__ rows,
                                                 const int* __restrict__ cols,
                                                 const float* __restrict__ vals,
                                                 uint* __restrict__ cur, uint2* __restrict__ stage,
                                                 int nnz, int nb) {
    __shared__ uint lh[NB_MAX];
    __shared__ uint gb[NB_MAX];
    long long beg = ((long long)blockIdx.x * nnz) / gridDim.x;
    long long end = ((long long)(blockIdx.x + 1) * nnz) / gridDim.x;
    for (int j = threadIdx.x; j < nb; j += blockDim.x) lh[j] = 0;
    __syncthreads();
    for (long long i = beg + threadIdx.x; i < end; i += blockDim.x)
        atomicAdd(&lh[rows[i] >> 6], 1u);
    __syncthreads();
    for (int j = threadIdx.x; j < nb; j += blockDim.x) {
        uint c = lh[j];
        gb[j] = c ? atomicAdd(&cur[j], c) : 0u;
        lh[j] = 0;
    }
    __syncthreads();
    for (long long i = beg + threadIdx.x; i < end; i += blockDim.x) {
        int r = rows[i];
        int b = r >> 6;
        uint pos = gb[b] + atomicAdd(&lh[b], 1u);
        uint c = (uint)__builtin_nontemporal_load(cols + i);
        float v = __builtin_nontemporal_load(vals + i);
        uint2 rec;
        rec.x = ((uint)(r & 63) << 17) | c;
        rec.y = __float_as_uint(v);
        stage[pos] = rec;
    }
}

// ---- fused gate + bf16 cast ----------------------------------------------
// one wave per node; lane h holds W1 row h in 128 VGPRs; x broadcast by shfl.

__global__ __launch_bounds__(256) void k_gatecast(const float* __restrict__ x,
                                                  const float* __restrict__ W1,
                                                  const float* __restrict__ b1,
                                                  const float* __restrict__ W2,
                                                  const float* __restrict__ b2,
                                                  float* __restrict__ alph,
                                                  ushort* __restrict__ xbf, int N) {
    int gid = blockIdx.x * blockDim.x + threadIdx.x;
    int wid = gid >> 6, lane = threadIdx.x & 63;
    int nw = (gridDim.x * blockDim.x) >> 6;
    float w[128];
#pragma unroll
    for (int j = 0; j < 32; j++) {
        float4 t4 = ((const float4*)(W1 + lane * 128))[j];
        w[4 * j] = t4.x; w[4 * j + 1] = t4.y; w[4 * j + 2] = t4.z; w[4 * j + 3] = t4.w;
    }
    float b1l = b1[lane], w2l = W2[lane], b2s = b2[0];
    for (int n = wid; n < N; n += nw) {
        float xa = x[(size_t)n * 128 + lane];
        float xb = x[(size_t)n * 128 + 64 + lane];
        xbf[(size_t)n * 128 + lane] = f2bf(xa);
        xbf[(size_t)n * 128 + 64 + lane] = f2bf(xb);
        float acc = b1l;
#pragma unroll
        for (int k = 0; k < 64; k++) acc = fmaf(__shfl(xa, k), w[k], acc);
#pragma unroll
        for (int k = 0; k < 64; k++) acc = fmaf(__shfl(xb, k), w[64 + k], acc);
        acc = fminf(fmaxf(acc, -10.f), 10.f);
        float p = acc * w2l;
#pragma unroll
        for (int o = 32; o > 0; o >>= 1) p += __shfl_xor(p, o);
        float a = 1.f / (1.f + __expf(-(p + b2s)));
        a = fminf(fmaxf(a, 1e-6f), 1.f - 1e-6f);
        if (lane == 0) alph[n] = a;
    }
}

// ---- SpMM over 64-row buckets with LDS f32 accumulation -------------------
// one block per bucket; per edge: 256B coalesced gather + 2 ds_add per lane.

__global__ __launch_bounds__(256) void k_spmm1(const uint* __restrict__ off,
                                               const uint2* __restrict__ stage,
                                               const ushort* __restrict__ xbf,
                                               ushort* __restrict__ axbf, int N) {
    __shared__ float acc[64 * 128];
    int b = blockIdx.x;
    int r0 = b << 6;
    int rcnt = min(64, N - r0);
    for (int k = threadIdx.x; k < 64 * 128; k += blockDim.x) acc[k] = 0.f;
    __syncthreads();
    uint s = off[b], e = off[b + 1];
    int lane = threadIdx.x & 63, wid = threadIdx.x >> 6;
    for (uint base = s + (uint)(wid << 6); base < e; base += 256u) {
        uint idx = base + (uint)lane;
        uint2 rec = (idx < e) ? stage[idx] : make_uint2(0u, 0u);
        int jmax = (int)min(64u, e - base);
        if (jmax == 64) {
#pragma unroll 8
            for (int j = 0; j < 64; j++) {
                uint pk = __shfl(rec.x, j);
                float v = __uint_as_float(__shfl(rec.y, j));
                int lrow = (int)(pk >> 17);
                int col = (int)(pk & 0x1FFFFu);
                uint g = *(const uint*)(xbf + ((size_t)col << 7) + (lane << 1));
                atomicAdd(&acc[(lrow << 7) + (lane << 1)], v * bf2f((ushort)(g & 0xffff)));
                atomicAdd(&acc[(lrow << 7) + (lane << 1) + 1], v * bf2f((ushort)(g >> 16)));
            }
        } else {
            for (int j = 0; j < jmax; j++) {
                uint pk = __shfl(rec.x, j);
                float v = __uint_as_float(__shfl(rec.y, j));
                int lrow = (int)(pk >> 17);
                int col = (int)(pk & 0x1FFFFu);
                uint g = *(const uint*)(xbf + ((size_t)col << 7) + (lane << 1));
                atomicAdd(&acc[(lrow << 7) + (lane << 1)], v * bf2f((ushort)(g & 0xffff)));
                atomicAdd(&acc[(lrow << 7) + (lane << 1) + 1], v * bf2f((ushort)(g >> 16)));
            }
        }
    }
    __syncthreads();
    for (int k = threadIdx.x; k < rcnt * 64; k += blockDim.x) {
        int lrow = k >> 6, c2 = k & 63;
        float f0 = acc[(lrow << 7) + (c2 << 1)];
        float f1 = acc[(lrow << 7) + (c2 << 1) + 1];
        uint pkd = ((uint)f2bf(f1) << 16) | (uint)f2bf(f0);
        *((uint*)axbf + ((size_t)(r0 + lrow) << 6) + c2) = pkd;
    }
}

__global__ __launch_bounds__(256) void k_spmm2(const uint* __restrict__ off,
                                               const uint2* __restrict__ stage,
                                               const ushort* __restrict__ axbf,
                                               const float* __restrict__ alph,
                                               const float* __restrict__ x,
                                               float* __restrict__ out, int N) {
    __shared__ float acc[64 * 128];
    int b = blockIdx.x;
    int r0 = b << 6;
    int rcnt = min(64, N - r0);
    for (int k = threadIdx.x; k < 64 * 128; k += blockDim.x) acc[k] = 0.f;
    __syncthreads();
    uint s = off[b], e = off[b + 1];
    int lane = threadIdx.x & 63, wid = threadIdx.x >> 6;
    for (uint base = s + (uint)(wid << 6); base < e; base += 256u) {
        uint idx = base + (uint)lane;
        uint2 rec = (idx < e) ? stage[idx] : make_uint2(0u, 0u);
        int jmax = (int)min(64u, e - base);
        if (jmax == 64) {
#pragma unroll 8
            for (int j = 0; j < 64; j++) {
                uint pk = __shfl(rec.x, j);
                float v = __uint_as_float(__shfl(rec.y, j));
                int lrow = (int)(pk >> 17);
                int col = (int)(pk & 0x1FFFFu);
                uint g = *(const uint*)(axbf + ((size_t)col << 7) + (lane << 1));
                atomicAdd(&acc[(lrow << 7) + (lane << 1)], v * bf2f((ushort)(g & 0xffff)));
                atomicAdd(&acc[(lrow << 7) + (lane << 1) + 1], v * bf2f((ushort)(g >> 16)));
            }
        } else {
            for (int j = 0; j < jmax; j++) {
                uint pk = __shfl(rec.x, j);
                float v = __uint_as_float(__shfl(rec.y, j));
                int lrow = (int)(pk >> 17);
                int col = (int)(pk & 0x1FFFFu);
                uint g = *(const uint*)(axbf + ((size_t)col << 7) + (lane << 1));
                atomicAdd(&acc[(lrow << 7) + (lane << 1)], v * bf2f((ushort)(g & 0xffff)));
                atomicAdd(&acc[(lrow << 7) + (lane << 1) + 1], v * bf2f((ushort)(g >> 16)));
            }
        }
    }
    __syncthreads();
    for (int k = threadIdx.x; k < rcnt * 64; k += blockDim.x) {
        int lrow = k >> 6, c2 = k & 63;
        int r = r0 + lrow;
        float al = alph[r];
        float2 xr = *(const float2*)(x + ((size_t)r << 7) + (c2 << 1));
        float2 o;
        o.x = fmaf(al, acc[(lrow << 7) + (c2 << 1)], -xr.x);
        o.y = fmaf(al, acc[(lrow << 7) + (c2 << 1) + 1], -xr.y);
        *((float2*)out + ((size_t)r << 6) + c2) = o;
    }
}

// ---- launch ---------------------------------------------------------------

extern "C" void kernel_launch(void* const* d_in, const int* in_sizes, int n_in,
                              void* d_out, int out_size, void* d_ws, size_t ws_size,
                              hipStream_t stream) {
    const float* x    = (const float*)d_in[1];
    const int*   rows = (const int*)d_in[2];
    const int*   cols = (const int*)d_in[3];
    const float* vals = (const float*)d_in[4];
    const float* W1 = (const float*)d_in[5];
    const float* b1 = (const float*)d_in[6];
    const float* W2 = (const float*)d_in[7];
    const float* b2 = (const float*)d_in[8];
    float* out = (float*)d_out;

    int N = in_sizes[1] / 128;
    int nnz = in_sizes[2];
    int nb = (N + 63) >> 6;   // 1563

    char* ws = (char*)d_ws;
    size_t off_b = 0;
    auto take = [&](size_t bytes) -> char* {
        size_t p = (off_b + 255) & ~(size_t)255;
        off_b = p + bytes;
        return ws + p;
    };
    uint2*  stage = (uint2*)take((size_t)nnz * 8);
    ushort* xbf   = (ushort*)take((size_t)N * 128 * 2);
    ushort* axbf  = (ushort*)take((size_t)N * 128 * 2);
    float*  alph  = (float*)take((size_t)N * 4);
    uint*   bhist = (uint*)take((size_t)(nb + 1) * 4);
    uint*   boff  = (uint*)take((size_t)(nb + 1) * 4);
    uint*   bcur  = (uint*)take((size_t)(nb + 1) * 4);
    (void)ws_size; (void)n_in; (void)out_size;

    hipMemsetAsync(bhist, 0, (size_t)nb * 4, stream);
    k_bhist<<<256, 256, 0, stream>>>(rows, bhist, nnz, nb);
    k_scan<<<1, 256, 0, stream>>>(bhist, boff, bcur, nb, nnz);
    k_binpass<<<196, 512, 0, stream>>>(rows, cols, vals, bcur, stage, nnz, nb);
    k_gatecast<<<512, 256, 0, stream>>>(x, W1, b1, W2, b2, alph, xbf, N);
    k_spmm1<<<nb, 256, 0, stream>>>(boff, stage, xbf, axbf, N);
    k_spmm2<<<nb, 256, 0, stream>>>(boff, stage, axbf, alph, x, out, N);
}

// Round 5
// 575.295 us; speedup vs baseline: 8.8505x; 8.8505x over previous
//
#include <hip/hip_runtime.h>
#include <stdint.h>

typedef unsigned int uint;
typedef unsigned short ushort;

#define NB_MAX 1600   // buckets = ceil(N/64); N=100000 -> 1563

__device__ __forceinline__ ushort f2bf(float f) {
    uint u = __float_as_uint(f);
    return (ushort)((u + 0x7fffu + ((u >> 16) & 1u)) >> 16);   // RNE
}
__device__ __forceinline__ float bf2f(ushort h) {
    return __uint_as_float(((uint)h) << 16);
}

// ---- bucket histogram (64-row buckets), LDS-aggregated --------------------

__global__ __launch_bounds__(256) void k_bhist(const int* __restrict__ rows,
                                               uint* __restrict__ bhist, int nnz, int nb) {
    __shared__ uint h[NB_MAX];
    for (int j = threadIdx.x; j < nb; j += blockDim.x) h[j] = 0;
    __syncthreads();
    int stride = gridDim.x * blockDim.x;
    for (int i = blockIdx.x * blockDim.x + threadIdx.x; i < nnz; i += stride)
        atomicAdd(&h[rows[i] >> 6], 1u);
    __syncthreads();
    for (int j = threadIdx.x; j < nb; j += blockDim.x) {
        uint c = h[j];
        if (c) atomicAdd(&bhist[j], c);
    }
}

// ---- single-block exclusive scan over nb buckets --------------------------

__global__ __launch_bounds__(256) void k_scan(const uint* __restrict__ bhist,
                                              uint* __restrict__ off, uint* __restrict__ cur,
                                              uint* __restrict__ row_off,
                                              int nb, int nnz, int N) {
    __shared__ uint wsum[4];
    __shared__ uint carry;
    int t = threadIdx.x, lane = t & 63, wv = t >> 6;
    if (t == 0) carry = 0;
    __syncthreads();
    for (int base = 0; base < nb; base += 256) {
        int i = base + t;
        uint v = (i < nb) ? bhist[i] : 0u;
        uint inc = v;
#pragma unroll
        for (int o = 1; o < 64; o <<= 1) { uint u = __shfl_up(inc, o); if (lane >= o) inc += u; }
        if (lane == 63) wsum[wv] = inc;
        __syncthreads();
        uint woff = 0;
        for (int k = 0; k < wv; k++) woff += wsum[k];
        uint excl = carry + woff + (inc - v);
        if (i < nb) { off[i] = excl; cur[i] = excl; }
        uint tot = wsum[0] + wsum[1] + wsum[2] + wsum[3];
        __syncthreads();
        if (t == 0) carry += tot;
        __syncthreads();
    }
    if (t == 0) { off[nb] = (uint)nnz; row_off[N] = (uint)nnz; }
}

// ---- two-pass binning: edges -> bucket-contiguous records -----------------
// record: (localrow6 << 17) | col17 , val. One global atomic per (bucket,block).

__global__ __launch_bounds__(512) void k_binpass(const int* __restrict__ rows,
                                                 const int* __restrict__ cols,
                                                 const float* __restrict__ vals,
                                                 uint* __restrict__ cur, uint2* __restrict__ stage,
                                                 int nnz, int nb) {
    __shared__ uint lh[NB_MAX];
    __shared__ uint gb[NB_MAX];
    long long beg = ((long long)blockIdx.x * nnz) / gridDim.x;
    long long end = ((long long)(blockIdx.x + 1) * nnz) / gridDim.x;
    for (int j = threadIdx.x; j < nb; j += blockDim.x) lh[j] = 0;
    __syncthreads();
    for (long long i = beg + threadIdx.x; i < end; i += blockDim.x)
        atomicAdd(&lh[rows[i] >> 6], 1u);
    __syncthreads();
    for (int j = threadIdx.x; j < nb; j += blockDim.x) {
        uint c = lh[j];
        gb[j] = c ? atomicAdd(&cur[j], c) : 0u;
        lh[j] = 0;
    }
    __syncthreads();
    for (long long i = beg + threadIdx.x; i < end; i += blockDim.x) {
        int r = rows[i];
        int b = r >> 6;
        uint pos = gb[b] + atomicAdd(&lh[b], 1u);
        uint c = (uint)__builtin_nontemporal_load(cols + i);
        float v = __builtin_nontemporal_load(vals + i);
        uint2 rec;
        rec.x = ((uint)(r & 63) << 17) | c;
        rec.y = __float_as_uint(v);
        stage[pos] = rec;
    }
}

// ---- per-bucket LDS counting sort: bucket-contiguous -> row-contiguous ----
// one block per bucket; scatter stays inside the bucket's ~16 KB region (L2-
// local, lines fully assembled -> write amp ~1). Emits per-row CSR offsets.

__global__ __launch_bounds__(256) void k_bsort(const uint* __restrict__ boff,
                                               const uint2* __restrict__ stage,
                                               uint2* __restrict__ sorted,
                                               uint* __restrict__ row_off,
                                               int N) {
    __shared__ uint rcnt[64], rcur[64];
    int b = blockIdx.x;
    uint s = boff[b], e = boff[b + 1];
    int t = threadIdx.x;
    if (t < 64) rcnt[t] = 0;
    __syncthreads();
    for (uint i = s + t; i < e; i += blockDim.x)
        atomicAdd(&rcnt[stage[i].x >> 17], 1u);
    __syncthreads();
    if (t < 64) {   // threads 0..63 are wave 0: exclusive scan of 64 counts
        uint v = rcnt[t];
        uint inc = v;
#pragma unroll
        for (int o = 1; o < 64; o <<= 1) { uint u = __shfl_up(inc, o); if (t >= o) inc += u; }
        rcur[t] = inc - v;
        int r = (b << 6) + t;
        if (r < N) row_off[r] = s + inc - v;
    }
    __syncthreads();
    for (uint i = s + t; i < e; i += blockDim.x) {
        uint2 rec = stage[i];
        uint lrow = rec.x >> 17;
        uint pos = atomicAdd(&rcur[lrow], 1u);
        uint2 o; o.x = rec.x & 0x1FFFFu; o.y = rec.y;
        sorted[s + pos] = o;
    }
}

// ---- fused gate + bf16 cast ----------------------------------------------
// one wave per node; lane h holds W1 row h in 128 VGPRs; x broadcast by shfl.
// NOTE: writes xbf which ALIASES stage -> must launch after k_bsort.

__global__ __launch_bounds__(256) void k_gatecast(const float* __restrict__ x,
                                                  const float* __restrict__ W1,
                                                  const float* __restrict__ b1,
                                                  const float* __restrict__ W2,
                                                  const float* __restrict__ b2,
                                                  float* __restrict__ alph,
                                                  ushort* __restrict__ xbf, int N) {
    int gid = blockIdx.x * blockDim.x + threadIdx.x;
    int wid = gid >> 6, lane = threadIdx.x & 63;
    int nw = (gridDim.x * blockDim.x) >> 6;
    float w[128];
#pragma unroll
    for (int j = 0; j < 32; j++) {
        float4 t4 = ((const float4*)(W1 + lane * 128))[j];
        w[4 * j] = t4.x; w[4 * j + 1] = t4.y; w[4 * j + 2] = t4.z; w[4 * j + 3] = t4.w;
    }
    float b1l = b1[lane], w2l = W2[lane], b2s = b2[0];
    for (int n = wid; n < N; n += nw) {
        float xa = x[(size_t)n * 128 + lane];
        float xb = x[(size_t)n * 128 + 64 + lane];
        xbf[(size_t)n * 128 + lane] = f2bf(xa);
        xbf[(size_t)n * 128 + 64 + lane] = f2bf(xb);
        float acc = b1l;
#pragma unroll
        for (int k = 0; k < 64; k++) acc = fmaf(__shfl(xa, k), w[k], acc);
#pragma unroll
        for (int k = 0; k < 64; k++) acc = fmaf(__shfl(xb, k), w[64 + k], acc);
        acc = fminf(fmaxf(acc, -10.f), 10.f);
        float p = acc * w2l;
#pragma unroll
        for (int o = 32; o > 0; o >>= 1) p += __shfl_xor(p, o);
        float a = 1.f / (1.f + __expf(-(p + b2s)));
        a = fminf(fmaxf(a, 1e-6f), 1.f - 1e-6f);
        if (lane == 0) alph[n] = a;
    }
}

// ---- SpMM: one wave per row, lane covers 2 of 128 columns, 4-edge unroll --

__global__ __launch_bounds__(256) void k_spmm1(const uint* __restrict__ roff,
                                               const uint2* __restrict__ recs,
                                               const ushort* __restrict__ xbf,
                                               ushort* __restrict__ axbf, int N) {
    int w = (blockIdx.x * blockDim.x + threadIdx.x) >> 6;
    int lane = threadIdx.x & 63;
    if (w >= N) return;
    uint beg = roff[w], end = roff[w + 1];
    float a0 = 0.f, a1 = 0.f, b0 = 0.f, b1 = 0.f, c0 = 0.f, c1 = 0.f, d0 = 0.f, d1 = 0.f;
    uint e = beg;
    for (; e + 4 <= end; e += 4) {
        uint2 q0 = recs[e], q1 = recs[e + 1], q2 = recs[e + 2], q3 = recs[e + 3];
        uint g0 = *(const uint*)(xbf + ((size_t)q0.x << 7) + (lane << 1));
        uint g1 = *(const uint*)(xbf + ((size_t)q1.x << 7) + (lane << 1));
        uint g2 = *(const uint*)(xbf + ((size_t)q2.x << 7) + (lane << 1));
        uint g3 = *(const uint*)(xbf + ((size_t)q3.x << 7) + (lane << 1));
        float v0 = __uint_as_float(q0.y), v1 = __uint_as_float(q1.y);
        float v2 = __uint_as_float(q2.y), v3 = __uint_as_float(q3.y);
        a0 = fmaf(v0, bf2f((ushort)(g0 & 0xffff)), a0); a1 = fmaf(v0, bf2f((ushort)(g0 >> 16)), a1);
        b0 = fmaf(v1, bf2f((ushort)(g1 & 0xffff)), b0); b1 = fmaf(v1, bf2f((ushort)(g1 >> 16)), b1);
        c0 = fmaf(v2, bf2f((ushort)(g2 & 0xffff)), c0); c1 = fmaf(v2, bf2f((ushort)(g2 >> 16)), c1);
        d0 = fmaf(v3, bf2f((ushort)(g3 & 0xffff)), d0); d1 = fmaf(v3, bf2f((ushort)(g3 >> 16)), d1);
    }
    for (; e < end; e++) {
        uint2 q0 = recs[e];
        float v0 = __uint_as_float(q0.y);
        uint g0 = *(const uint*)(xbf + ((size_t)q0.x << 7) + (lane << 1));
        a0 = fmaf(v0, bf2f((ushort)(g0 & 0xffff)), a0);
        a1 = fmaf(v0, bf2f((ushort)(g0 >> 16)), a1);
    }
    a0 += b0 + c0 + d0; a1 += b1 + c1 + d1;
    uint packed = ((uint)f2bf(a1) << 16) | (uint)f2bf(a0);
    *((uint*)axbf + ((size_t)w << 6) + lane) = packed;
}

__global__ __launch_bounds__(256) void k_spmm2(const uint* __restrict__ roff,
                                               const uint2* __restrict__ recs,
                                               const ushort* __restrict__ axbf,
                                               const float* __restrict__ alph,
                                               const float* __restrict__ x,
                                               float* __restrict__ out, int N) {
    int w = (blockIdx.x * blockDim.x + threadIdx.x) >> 6;
    int lane = threadIdx.x & 63;
    if (w >= N) return;
    uint beg = roff[w], end = roff[w + 1];
    float a0 = 0.f, a1 = 0.f, b0 = 0.f, b1 = 0.f, c0 = 0.f, c1 = 0.f, d0 = 0.f, d1 = 0.f;
    uint e = beg;
    for (; e + 4 <= end; e += 4) {
        uint2 q0 = recs[e], q1 = recs[e + 1], q2 = recs[e + 2], q3 = recs[e + 3];
        uint g0 = *(const uint*)(axbf + ((size_t)q0.x << 7) + (lane << 1));
        uint g1 = *(const uint*)(axbf + ((size_t)q1.x << 7) + (lane << 1));
        uint g2 = *(const uint*)(axbf + ((size_t)q2.x << 7) + (lane << 1));
        uint g3 = *(const uint*)(axbf + ((size_t)q3.x << 7) + (lane << 1));
        float v0 = __uint_as_float(q0.y), v1 = __uint_as_float(q1.y);
        float v2 = __uint_as_float(q2.y), v3 = __uint_as_float(q3.y);
        a0 = fmaf(v0, bf2f((ushort)(g0 & 0xffff)), a0); a1 = fmaf(v0, bf2f((ushort)(g0 >> 16)), a1);
        b0 = fmaf(v1, bf2f((ushort)(g1 & 0xffff)), b0); b1 = fmaf(v1, bf2f((ushort)(g1 >> 16)), b1);
        c0 = fmaf(v2, bf2f((ushort)(g2 & 0xffff)), c0); c1 = fmaf(v2, bf2f((ushort)(g2 >> 16)), c1);
        d0 = fmaf(v3, bf2f((ushort)(g3 & 0xffff)), d0); d1 = fmaf(v3, bf2f((ushort)(g3 >> 16)), d1);
    }
    for (; e < end; e++) {
        uint2 q0 = recs[e];
        float v0 = __uint_as_float(q0.y);
        uint g0 = *(const uint*)(axbf + ((size_t)q0.x << 7) + (lane << 1));
        a0 = fmaf(v0, bf2f((ushort)(g0 & 0xffff)), a0);
        a1 = fmaf(v0, bf2f((ushort)(g0 >> 16)), a1);
    }
    a0 += b0 + c0 + d0; a1 += b1 + c1 + d1;
    float al = alph[w];
    float2 xr = *(const float2*)(x + ((size_t)w << 7) + (lane << 1));
    float2 o; o.x = fmaf(al, a0, -xr.x); o.y = fmaf(al, a1, -xr.y);
    *((float2*)out + ((size_t)w << 6) + lane) = o;
}

// ---- launch ---------------------------------------------------------------

extern "C" void kernel_launch(void* const* d_in, const int* in_sizes, int n_in,
                              void* d_out, int out_size, void* d_ws, size_t ws_size,
                              hipStream_t stream) {
    const float* x    = (const float*)d_in[1];
    const int*   rows = (const int*)d_in[2];
    const int*   cols = (const int*)d_in[3];
    const float* vals = (const float*)d_in[4];
    const float* W1 = (const float*)d_in[5];
    const float* b1 = (const float*)d_in[6];
    const float* W2 = (const float*)d_in[7];
    const float* b2 = (const float*)d_in[8];
    float* out = (float*)d_out;

    int N = in_sizes[1] / 128;
    int nnz = in_sizes[2];
    int nb = (N + 63) >> 6;   // 1563

    char* ws = (char*)d_ws;
    size_t off_b = 0;
    auto take = [&](size_t bytes) -> char* {
        size_t p = (off_b + 255) & ~(size_t)255;
        off_b = p + bytes;
        return ws + p;
    };
    // stage (binpass output) aliases xbf: stage is dead after k_bsort, and
    // k_gatecast (which writes xbf) launches after k_bsort on the same stream.
    char*   stage_or_xbf = take((size_t)nnz * 8 > (size_t)N * 256 ? (size_t)nnz * 8 : (size_t)N * 256);
    uint2*  stage  = (uint2*)stage_or_xbf;
    ushort* xbf    = (ushort*)stage_or_xbf;
    uint2*  sorted = (uint2*)take((size_t)nnz * 8);
    ushort* axbf   = (ushort*)take((size_t)N * 128 * 2);
    float*  alph   = (float*)take((size_t)N * 4);
    uint*   bhist  = (uint*)take((size_t)(nb + 1) * 4);
    uint*   boff   = (uint*)take((size_t)(nb + 1) * 4);
    uint*   bcur   = (uint*)take((size_t)(nb + 1) * 4);
    uint*   row_off = (uint*)take((size_t)(N + 1) * 4);
    (void)ws_size; (void)n_in; (void)out_size;

    hipMemsetAsync(bhist, 0, (size_t)nb * 4, stream);
    k_bhist<<<120, 256, 0, stream>>>(rows, bhist, nnz, nb);
    k_scan<<<1, 256, 0, stream>>>(bhist, boff, bcur, row_off, nb, nnz, N);
    k_binpass<<<196, 512, 0, stream>>>(rows, cols, vals, bcur, stage, nnz, nb);
    k_bsort<<<nb, 256, 0, stream>>>(boff, stage, sorted, row_off, N);
    k_gatecast<<<512, 256, 0, stream>>>(x, W1, b1, W2, b2, alph, xbf, N);
    k_spmm1<<<((N * 64) + 255) / 256, 256, 0, stream>>>(row_off, sorted, xbf, axbf, N);
    k_spmm2<<<((N * 64) + 255) / 256, 256, 0, stream>>>(row_off, sorted, axbf, alph, x, out, N);
}